// Round 4
// baseline (285.106 us; speedup 1.0000x reference)
//
#include <hip/hip_runtime.h>

typedef __attribute__((ext_vector_type(8))) short bf16x8;
typedef __attribute__((ext_vector_type(16))) float f32x16;

__device__ __forceinline__ unsigned short f2b(float f) {
  unsigned x = __builtin_bit_cast(unsigned, f);
  x += 0x7fffu + ((x >> 16) & 1u);   // round-to-nearest-even
  return (unsigned short)(x >> 16);
}

// ---------------------------------------------------------------------------
// Kernel 0: W [768][384] fp32 -> Wt [384][768] bf16; Y -> Ybf bf16 + y2 fp32
// Y work spread over 8 blocks (was 1) to avoid a single-block straggler.
// ---------------------------------------------------------------------------
__global__ __launch_bounds__(256) void k_prep(const float* __restrict__ W,
                                              const float* __restrict__ Y,
                                              unsigned short* __restrict__ Wt,
                                              unsigned short* __restrict__ Ybf,
                                              float* __restrict__ y2) {
  __shared__ unsigned short sT[64][72];
  int b = blockIdx.x;
  if (b < 72) {
    int bk = (b % 12) * 64, bn = (b / 12) * 64;
    int c = threadIdx.x & 63, rr = threadIdx.x >> 6;
#pragma unroll
    for (int i = 0; i < 16; i++) {
      int row = rr * 16 + i;
      sT[row][c] = f2b(W[(size_t)(bk + row) * 384 + bn + c]);
    }
    __syncthreads();
#pragma unroll
    for (int i = 0; i < 16; i++) {
      int row = rr * 16 + i;
      Wt[(size_t)(bn + row) * 768 + bk + c] = sT[c][row];
    }
  } else {
    int yb = b - 72;  // [0,8)
    int t = threadIdx.x;
    // convert 12288 float4 total; 1536 per block
#pragma unroll
    for (int i = 0; i < 6; i++) {
      int idx = yb * 1536 + i * 256 + t;
      float4 v = ((const float4*)Y)[idx];
      ushort4 o;
      o.x = f2b(v.x); o.y = f2b(v.y); o.z = f2b(v.z); o.w = f2b(v.w);
      ((ushort4*)Ybf)[idx] = o;
    }
    // y2: 16 rows per block, 8 lanes per row
    if (t < 128) {
      int row = yb * 16 + (t >> 3), j = t & 7;
      const float4* rp = (const float4*)(Y + (size_t)row * 384);
      float s = 0.f;
#pragma unroll
      for (int i = 0; i < 12; i++) {
        float4 v = rp[j + i * 8];
        s += v.x * v.x + v.y * v.y + v.z * v.z + v.w * v.w;
      }
      s += __shfl_xor(s, 1);
      s += __shfl_xor(s, 2);
      s += __shfl_xor(s, 4);
      if (j == 0) y2[row] = s;
    }
  }
}

// ---------------------------------------------------------------------------
// Kernel 1: projected = cls @ W + b (fused expmap0) -> fp32 x, fp32 x2
//   M=64/block, grid 512 (2 blocks/CU), 512 thr = 8 waves of 32x96
//   Two-phase batched staging + cross-iteration register prefetch.
// ---------------------------------------------------------------------------
#define LDS1 72  // 64 + 8 pad shorts; 144 B row stride (conflict-minimal)

__global__ __launch_bounds__(512, 4) void k_proj(const float* __restrict__ cls,
                                                 const unsigned short* __restrict__ Wt,
                                                 const float* __restrict__ bias,
                                                 float* __restrict__ xout,
                                                 float* __restrict__ x2out) {
  __shared__ unsigned short sA[64 * LDS1];   // 9216 B
  __shared__ unsigned short sW[384 * LDS1];  // 55296 B
  __shared__ float rs[64][4];
  __shared__ float sF[64];

  const int tid = threadIdx.x;
  const int bm = blockIdx.x * 64;
  const int wave = tid >> 6, lane = tid & 63;
  const int r = lane & 31, h = lane >> 5;
  const int rg = wave & 1, cg = wave >> 1;  // rows rg*32, cols cg*96

  // staging thread->element maps (fixed across iters)
  const int arow = tid >> 3, akc = tid & 7;        // A: 64 rows x 8 chunks
  const float* aptr = cls + (size_t)(bm + arow) * 768 + akc * 8;
  const unsigned short* asd = sA + arow * LDS1 + akc * 8;

  f32x16 acc[3];
#pragma unroll
  for (int j = 0; j < 3; j++)
#pragma unroll
    for (int e = 0; e < 16; e++) acc[j][e] = 0.f;

  uint4 wv[6];
  float4 af0, af1;

  // prologue: load k0 = 0
#pragma unroll
  for (int i = 0; i < 6; i++) {
    int c = tid + i * 512, row = c >> 3, kc = c & 7;
    wv[i] = *(const uint4*)(Wt + (size_t)row * 768 + kc * 8);
  }
  af0 = *(const float4*)(aptr);
  af1 = *(const float4*)(aptr + 4);

  for (int k0 = 0; k0 < 768; k0 += 64) {
    __syncthreads();  // prev MFMA readers done
    // phase 2: convert + write all staged data
    uint4 ap;
    ap.x = (unsigned)f2b(af0.x) | ((unsigned)f2b(af0.y) << 16);
    ap.y = (unsigned)f2b(af0.z) | ((unsigned)f2b(af0.w) << 16);
    ap.z = (unsigned)f2b(af1.x) | ((unsigned)f2b(af1.y) << 16);
    ap.w = (unsigned)f2b(af1.z) | ((unsigned)f2b(af1.w) << 16);
    *(uint4*)asd = ap;
#pragma unroll
    for (int i = 0; i < 6; i++) {
      int c = tid + i * 512, row = c >> 3, kc = c & 7;
      *(uint4*)(sW + row * LDS1 + kc * 8) = wv[i];
    }
    __syncthreads();
    // phase 3: prefetch next K-chunk (flies during MFMA below)
    if (k0 + 64 < 768) {
      int kn = k0 + 64;
#pragma unroll
      for (int i = 0; i < 6; i++) {
        int c = tid + i * 512, row = c >> 3, kc = c & 7;
        wv[i] = *(const uint4*)(Wt + (size_t)row * 768 + kn + kc * 8);
      }
      af0 = *(const float4*)(aptr + kn);
      af1 = *(const float4*)(aptr + kn + 4);
    }
    // phase 4: MFMA on current LDS contents
#pragma unroll
    for (int sub = 0; sub < 4; sub++) {
      const int kk = sub * 16 + h * 8;
      bf16x8 a = *(const bf16x8*)(sA + (rg * 32 + r) * LDS1 + kk);
      bf16x8 b0 = *(const bf16x8*)(sW + (cg * 96 + r) * LDS1 + kk);
      bf16x8 b1 = *(const bf16x8*)(sW + (cg * 96 + 32 + r) * LDS1 + kk);
      bf16x8 b2 = *(const bf16x8*)(sW + (cg * 96 + 64 + r) * LDS1 + kk);
      acc[0] = __builtin_amdgcn_mfma_f32_32x32x16_bf16(a, b0, acc[0], 0, 0, 0);
      acc[1] = __builtin_amdgcn_mfma_f32_32x32x16_bf16(a, b1, acc[1], 0, 0, 0);
      acc[2] = __builtin_amdgcn_mfma_f32_32x32x16_bf16(a, b2, acc[2], 0, 0, 0);
    }
  }

  // epilogue: bias + row sum-of-squares (wave covers 96 of 384 cols)
  float bcol[3];
#pragma unroll
  for (int j = 0; j < 3; j++) bcol[j] = bias[cg * 96 + j * 32 + r];

#pragma unroll
  for (int reg = 0; reg < 16; reg++) {
    float s = 0.f;
#pragma unroll
    for (int j = 0; j < 3; j++) {
      float v = acc[j][reg] + bcol[j];
      acc[j][reg] = v;
      s += v * v;
    }
    s += __shfl_xor(s, 1);
    s += __shfl_xor(s, 2);
    s += __shfl_xor(s, 4);
    s += __shfl_xor(s, 8);
    s += __shfl_xor(s, 16);
    if (r == 0) {
      int rowl = rg * 32 + (reg & 3) + 8 * (reg >> 2) + 4 * h;
      rs[rowl][cg] = s;
    }
  }
  __syncthreads();
  if (tid < 64) {
    float n2 = rs[tid][0] + rs[tid][1] + rs[tid][2] + rs[tid][3];
    float n = fmaxf(sqrtf(n2), 1e-15f);
    float f = tanhf(n) / n;
    sF[tid] = f;
    x2out[bm + tid] = n2 * f * f;  // fp32 (clip-sensitivity)
  }
  __syncthreads();
#pragma unroll
  for (int reg = 0; reg < 16; reg++) {
    int rowl = rg * 32 + (reg & 3) + 8 * (reg >> 2) + 4 * h;
    float f = sF[rowl];
#pragma unroll
    for (int j = 0; j < 3; j++) {
      xout[(size_t)(bm + rowl) * 384 + cg * 96 + j * 32 + r] = acc[j][reg] * f;
    }
  }
}

// ---------------------------------------------------------------------------
// Kernel 2: xy = x @ y^T + fused Poincare distance (fp32 in/out)
//   M=64/block, grid 512, 8 waves of 32x32, BK=128 (3 iters), prefetched.
// ---------------------------------------------------------------------------
#define LDS2 136  // 128 + 8 pad; 272 B row stride

__global__ __launch_bounds__(512, 4) void k_logits(const float* __restrict__ X,
                                                   const float* __restrict__ x2,
                                                   const unsigned short* __restrict__ Y,
                                                   const float* __restrict__ y2,
                                                   float* __restrict__ out) {
  __shared__ unsigned short sX[64 * LDS2];   // 17408 B
  __shared__ unsigned short sY[128 * LDS2];  // 34816 B
  const int tid = threadIdx.x;
  const int bm = blockIdx.x * 64;
  const int wave = tid >> 6, lane = tid & 63;
  const int r = lane & 31, h = lane >> 5;
  const int rt = 32 * (wave & 1), ct = 32 * (wave >> 1);

  const int xrow = tid >> 3, xkc = tid & 7;  // 64 rows x 8 chunks of 16 floats
  const float* xptr = X + (size_t)(bm + xrow) * 384 + xkc * 16;

  f32x16 acc;
#pragma unroll
  for (int e = 0; e < 16; e++) acc[e] = 0.f;

  float4 xf[4];
  uint4 yv[4];

  // prologue k0=0
#pragma unroll
  for (int i = 0; i < 4; i++) xf[i] = *(const float4*)(xptr + i * 4);
#pragma unroll
  for (int i = 0; i < 4; i++) {
    int c = tid + i * 512, row = c >> 4, kc = c & 15;
    yv[i] = *(const uint4*)(Y + (size_t)row * 384 + kc * 8);
  }

  for (int k0 = 0; k0 < 384; k0 += 128) {
    __syncthreads();
    uint4 p0, p1;
    p0.x = (unsigned)f2b(xf[0].x) | ((unsigned)f2b(xf[0].y) << 16);
    p0.y = (unsigned)f2b(xf[0].z) | ((unsigned)f2b(xf[0].w) << 16);
    p0.z = (unsigned)f2b(xf[1].x) | ((unsigned)f2b(xf[1].y) << 16);
    p0.w = (unsigned)f2b(xf[1].z) | ((unsigned)f2b(xf[1].w) << 16);
    p1.x = (unsigned)f2b(xf[2].x) | ((unsigned)f2b(xf[2].y) << 16);
    p1.y = (unsigned)f2b(xf[2].z) | ((unsigned)f2b(xf[2].w) << 16);
    p1.z = (unsigned)f2b(xf[3].x) | ((unsigned)f2b(xf[3].y) << 16);
    p1.w = (unsigned)f2b(xf[3].z) | ((unsigned)f2b(xf[3].w) << 16);
    *(uint4*)(sX + xrow * LDS2 + xkc * 16) = p0;
    *(uint4*)(sX + xrow * LDS2 + xkc * 16 + 8) = p1;
#pragma unroll
    for (int i = 0; i < 4; i++) {
      int c = tid + i * 512, row = c >> 4, kc = c & 15;
      *(uint4*)(sY + row * LDS2 + kc * 8) = yv[i];
    }
    __syncthreads();
    if (k0 + 128 < 384) {
      int kn = k0 + 128;
#pragma unroll
      for (int i = 0; i < 4; i++) xf[i] = *(const float4*)(xptr + kn + i * 4);
#pragma unroll
      for (int i = 0; i < 4; i++) {
        int c = tid + i * 512, row = c >> 4, kc = c & 15;
        yv[i] = *(const uint4*)(Y + (size_t)row * 384 + kn + kc * 8);
      }
    }
#pragma unroll
    for (int sub = 0; sub < 8; sub++) {
      const int kk = sub * 16 + h * 8;
      bf16x8 a = *(const bf16x8*)(sX + (rt + r) * LDS2 + kk);
      bf16x8 b = *(const bf16x8*)(sY + (ct + r) * LDS2 + kk);
      acc = __builtin_amdgcn_mfma_f32_32x32x16_bf16(a, b, acc, 0, 0, 0);
    }
  }

  const float CLIP = 0.9999800001f;  // (1 - 1e-5)^2
  float yc = y2[ct + r];
#pragma unroll
  for (int reg = 0; reg < 16; reg++) {
    int rowl = rt + (reg & 3) + 8 * (reg >> 2) + 4 * h;
    float xr = x2[bm + rowl];
    float xy = acc[reg];
    float sq = xr + yc - 2.f * xy;
    float den = 1.f - 2.f * xy + xr * yc;
    float ratio = fminf(fmaxf(sq / den, 0.f), CLIP);
    float s = sqrtf(ratio);
    float dist = logf((1.f + s) / (1.f - s));  // 2*atanh(s)
    out[(size_t)(bm + rowl) * 128 + ct + r] = -dist;
  }
}

// ---------------------------------------------------------------------------
extern "C" void kernel_launch(void* const* d_in, const int* in_sizes, int n_in,
                              void* d_out, int out_size, void* d_ws, size_t ws_size,
                              hipStream_t stream) {
  const float* cls  = (const float*)d_in[0];  // [32768][768] fp32
  const float* W    = (const float*)d_in[1];  // [768][384] fp32
  const float* bias = (const float*)d_in[2];  // [384] fp32
  const float* Y    = (const float*)d_in[3];  // [128][384] fp32

  float* out_logits = (float*)d_out;                 // [32768][128] fp32
  float* out_x = out_logits + (size_t)32768 * 128;   // [32768][384] fp32

  float* x2 = (float*)d_ws;                          // 32768 fp32
  float* y2 = x2 + 32768;                            // 128 fp32
  unsigned short* Wt = (unsigned short*)(y2 + 128);  // [384][768] bf16
  unsigned short* Ybf = Wt + (size_t)384 * 768;      // [128][384] bf16

  k_prep<<<80, 256, 0, stream>>>(W, Y, Wt, Ybf, y2);
  k_proj<<<512, 512, 0, stream>>>(cls, Wt, bias, out_x, x2);
  k_logits<<<512, 512, 0, stream>>>(out_x, x2, Ybf, y2, out_logits);
}